// Round 8
// baseline (306.963 us; speedup 1.0000x reference)
//
#include <hip/hip_runtime.h>
#include <math.h>

#define NN 100000
#define EE 1600000
#define GG 100
#define DIN 128
#define F1 128
#define FOUT 16

#define C1CAP 16384
#define C0CAP 49152
#define L2CAP 32768
#define DEGCAP 128   // max in-degree per S1 dst (mean ~17, Poisson; 128 is >±25 sigma)
#define NT 16        // nodes per h1lin tile

// ---- workspace layout (word offsets) ----
// zeroed region (single memset):
#define O_CNT      0                         // [0]=c1,[1]=c0,[3]=l2,[7]=done
#define O_FLAG1    (O_CNT + 8)               // int[NN]
#define O_FLAG0    (O_FLAG1 + NN)            // int[NN]
#define O_ISROOT   (O_FLAG0 + NN)            // int[NN]  (g+1, 0 = not root)
#define O_FILL     (O_ISROOT + NN)           // int[C1CAP]
#define O_ZEND     (O_FILL + C1CAP)
// 0xFF region:
#define O_ROOT     (O_ZEND)                  // uint[GG]
// written-before-read:
#define O_MAP1     (O_ROOT + GG)             // int[NN]
#define O_MAP0     (O_MAP1 + NN)             // int[NN]
#define O_LIST1    (O_MAP0 + NN)             // int[C1CAP]
#define O_LIST0    (O_LIST1 + C1CAP)         // int[C0CAP]
#define O_L2       (O_LIST0 + C0CAP)         // int[L2CAP*2] (src, g)
#define O_ORDER    (O_L2 + L2CAP*2)          // int[C1CAP*DEGCAP] src nodes per dst
#define O_H1       (O_ORDER + C1CAP*DEGCAP)  // float[C0CAP*F1]
#define O_A1S      (O_H1 + C0CAP*F1)         // float[C0CAP*4]
#define O_A1D      (O_A1S + C0CAP*4)         // float[C0CAP*4]
#define O_H2       (O_A1D + C0CAP*4)         // float[C1CAP*FOUT]
#define O_A2S      (O_H2 + C1CAP*FOUT)       // float[C1CAP]
#define O_A2D      (O_A2S + C1CAP)           // float[C1CAP]
#define O_END      (O_A2D + C1CAP)

// roots: group-min of nodes with x[:,0]==0; last block claims roots (fused mark)
__global__ __launch_bounds__(256) void gat_roots(
    const float* __restrict__ x, const int* __restrict__ batch, int* ws) {
  int i = blockIdx.x * blockDim.x + threadIdx.x;
  if (i < NN && x[(size_t)i * DIN] == 0.f)
    atomicMin((unsigned int*)&ws[O_ROOT + batch[i]], (unsigned int)i);
  __threadfence();
  __syncthreads();
  __shared__ int lastFlag;
  if (threadIdx.x == 0)
    lastFlag = (atomicAdd(&ws[O_CNT + 7], 1) == (int)gridDim.x - 1);
  __syncthreads();
  if (!lastFlag) return;
  int g = threadIdx.x;
  if (g >= GG) return;
  unsigned int r = __hip_atomic_load((unsigned int*)&ws[O_ROOT + g],
                                     __ATOMIC_ACQUIRE, __HIP_MEMORY_SCOPE_AGENT);
  if (r >= NN) return;
  ws[O_ISROOT + r] = g + 1;
  ws[O_FLAG1 + r] = 1;
  int idx = atomicAdd(&ws[O_CNT + 0], 1);
  if (idx < C1CAP) {
    ws[O_MAP1 + r] = idx;
    ws[O_LIST1 + idx] = r;
    ws[O_FILL + idx] = 1;                 // layer-1 self-loop pre-seeded
    ws[O_ORDER + idx * DEGCAP] = (int)r;
  }
  int p = atomicAdd(&ws[O_CNT + 3], 1);   // layer-2 self-loop (r -> g)
  if (p < L2CAP) { ws[O_L2 + 2*p] = (int)r; ws[O_L2 + 2*p + 1] = g; }
  ws[O_FLAG0 + r] = 1;
  int i0 = atomicAdd(&ws[O_CNT + 1], 1);
  if (i0 < C0CAP) { ws[O_MAP0 + r] = i0; ws[O_LIST0 + i0] = (int)r; }
}

// scan2: edges into roots -> L2 pairs (src,g); claim srcs into S1 (+S0, +self-loop)
#define SB2 1600
__global__ __launch_bounds__(256) void gat_scan2(const int* __restrict__ ei, int* __restrict__ ws) {
  __shared__ int sp[SB2 * 2];
  __shared__ int sc[SB2];
  __shared__ int nP, nC, bP, bC, b0;
  if (threadIdx.x == 0) { nP = 0; nC = 0; }
  __syncthreads();
  const int perBlock = (EE + gridDim.x - 1) / gridDim.x;   // 1563 <= SB2
  const int beg = blockIdx.x * perBlock;
  const int end = min(beg + perBlock, EE);
  for (int e = beg + threadIdx.x; e < end; e += 256) {
    int d = ei[EE + e];
    int gi = ws[O_ISROOT + d];
    if (gi) {
      int s = ei[e];
      int p = atomicAdd(&nP, 1);
      sp[2*p] = s; sp[2*p + 1] = gi - 1;
      if (atomicCAS(&ws[O_FLAG1 + s], 0, 1) == 0)
        sc[atomicAdd(&nC, 1)] = s;
    }
  }
  __syncthreads();
  if (threadIdx.x == 0) {
    bP = nP ? atomicAdd(&ws[O_CNT + 3], nP) : 0;
    bC = nC ? atomicAdd(&ws[O_CNT + 0], nC) : 0;
    b0 = nC ? atomicAdd(&ws[O_CNT + 1], nC) : 0;
  }
  __syncthreads();
  for (int i = threadIdx.x; i < nP; i += 256) {
    int p = bP + i;
    if (p < L2CAP) { ws[O_L2 + 2*p] = sp[2*i]; ws[O_L2 + 2*p + 1] = sp[2*i + 1]; }
  }
  for (int i = threadIdx.x; i < nC; i += 256) {
    int node = sc[i], idx = bC + i, i0 = b0 + i;
    if (idx < C1CAP) {
      ws[O_MAP1 + node] = idx;
      ws[O_LIST1 + idx] = node;
      ws[O_FILL + idx] = 1;               // self-loop
      ws[O_ORDER + idx * DEGCAP] = node;
    }
    ws[O_FLAG0 + node] = 1;               // unique nodes: plain store ok
    if (i0 < C0CAP) { ws[O_MAP0 + node] = i0; ws[O_LIST0 + i0] = node; }
  }
}

// scan1: edges into S1 -> direct scatter into per-dst slots; claim srcs into S0
__global__ __launch_bounds__(256) void gat_scan1(const int* __restrict__ ei, int* __restrict__ ws) {
  __shared__ int sc[SB2];
  __shared__ int nC, b0;
  if (threadIdx.x == 0) nC = 0;
  __syncthreads();
  const int perBlock = (EE + gridDim.x - 1) / gridDim.x;
  const int beg = blockIdx.x * perBlock;
  const int end = min(beg + perBlock, EE);
  for (int e = beg + threadIdx.x; e < end; e += 256) {
    int d = ei[EE + e];
    if (ws[O_FLAG1 + d]) {
      int s = ei[e];
      int md1 = ws[O_MAP1 + d];
      if ((unsigned)md1 < C1CAP) {
        int pos = atomicAdd(&ws[O_FILL + md1], 1);
        if (pos < DEGCAP) ws[O_ORDER + md1 * DEGCAP + pos] = s;
      }
      if (atomicCAS(&ws[O_FLAG0 + s], 0, 1) == 0)
        sc[atomicAdd(&nC, 1)] = s;
    }
  }
  __syncthreads();
  if (threadIdx.x == 0) b0 = nC ? atomicAdd(&ws[O_CNT + 1], nC) : 0;
  __syncthreads();
  for (int i = threadIdx.x; i < nC; i += 256) {
    int node = sc[i], i0 = b0 + i;
    if (i0 < C0CAP) { ws[O_MAP0 + node] = i0; ws[O_LIST0 + i0] = node; }
  }
}

// h1lin: 16-node tiles, x in LDS, W1 streamed (L1/L2); 8 nodes x 1 col per thread
__global__ __launch_bounds__(256) void gat_h1lin(
    const float* __restrict__ x, const float* __restrict__ W1,
    const float* __restrict__ att_s1, const float* __restrict__ att_d1, int* ws) {
  __shared__ float xs[NT][DIN];   // 8 KB
  int t = threadIdx.x, col = t & 127, half = t >> 7;
  int c0 = ws[O_CNT + 1]; if (c0 > C0CAP) c0 = C0CAP;
  float* h1  = (float*)(ws + O_H1);
  float* a1s = (float*)(ws + O_A1S);
  float* a1d = (float*)(ws + O_A1D);
  float as1v = att_s1[col], ad1v = att_d1[col];
  for (int tile = blockIdx.x * NT; tile < c0; tile += gridDim.x * NT) {
    {
      int n = t >> 4, k0 = (t & 15) * 8;
      int ci = tile + n;
      if (ci < c0) {
        int v = ws[O_LIST0 + ci];
        const float4* src = (const float4*)&x[(size_t)v * DIN + k0];
        *(float4*)&xs[n][k0]     = src[0];
        *(float4*)&xs[n][k0 + 4] = src[1];
      }
    }
    __syncthreads();
    float acc[8];
    #pragma unroll
    for (int i = 0; i < 8; ++i) acc[i] = 0.f;
    #pragma unroll 4
    for (int k = 0; k < DIN; k += 4) {
      float w0 = W1[(k + 0) * F1 + col];
      float w1 = W1[(k + 1) * F1 + col];
      float w2 = W1[(k + 2) * F1 + col];
      float w3 = W1[(k + 3) * F1 + col];
      #pragma unroll
      for (int n8 = 0; n8 < 8; ++n8) {
        const float4 xv = *(const float4*)&xs[half * 8 + n8][k];
        acc[n8] = fmaf(xv.x, w0, acc[n8]);
        acc[n8] = fmaf(xv.y, w1, acc[n8]);
        acc[n8] = fmaf(xv.z, w2, acc[n8]);
        acc[n8] = fmaf(xv.w, w3, acc[n8]);
      }
    }
    #pragma unroll
    for (int n8 = 0; n8 < 8; ++n8) {
      int ci = tile + half * 8 + n8;
      bool ok = ci < c0;
      if (ok) h1[(size_t)ci * F1 + col] = acc[n8];
      float cs = acc[n8] * as1v, cd = acc[n8] * ad1v;
      #pragma unroll
      for (int off = 16; off > 0; off >>= 1) {
        cs += __shfl_down(cs, off, 32);
        cd += __shfl_down(cd, off, 32);
      }
      if (ok && (col & 31) == 0) {
        a1s[ci * 4 + (col >> 5)] = cs;
        a1d[ci * 4 + (col >> 5)] = cd;
      }
    }
    __syncthreads();
  }
}

// e1agg (+fused layer-1 finalize + layer-2 linear): one block per S1 dst
__global__ __launch_bounds__(256) void gat_e1agg(
    const float* __restrict__ b1, const float* __restrict__ W2,
    const float* __restrict__ att_s2, const float* __restrict__ att_d2, int* ws) {
  int c1 = ws[O_CNT + 0]; if (c1 > C1CAP) c1 = C1CAP;
  float* a1s = (float*)(ws + O_A1S);
  float* a1d = (float*)(ws + O_A1D);
  float* h1  = (float*)(ws + O_H1);
  float* h2  = (float*)(ws + O_H2);
  float* a2s = (float*)(ws + O_A2S);
  float* a2d = (float*)(ws + O_A2D);
  __shared__ int   msBuf[DEGCAP];
  __shared__ float wBuf[DEGCAP * 4];
  __shared__ float sacc[2][F1];
  __shared__ float hs[F1];
  __shared__ float s1L[4];
  __shared__ float h2row[FOUT];
  int t = threadIdx.x, col = t & 127, half = t >> 7;
  for (int ci = blockIdx.x; ci < c1; ci += gridDim.x) {
    int cnt = ws[O_FILL + ci]; if (cnt > DEGCAP) cnt = DEGCAP;
    int node = ws[O_LIST1 + ci];
    int md0 = ws[O_MAP0 + node]; if ((unsigned)md0 >= C0CAP) md0 = 0;
    if (t < cnt) {
      int srcn = ws[O_ORDER + ci * DEGCAP + t];
      int ms = ws[O_MAP0 + srcn]; if ((unsigned)ms >= C0CAP) ms = 0;
      msBuf[t] = ms;
      #pragma unroll
      for (int h = 0; h < 4; ++h) {
        float ev = a1s[ms * 4 + h] + a1d[md0 * 4 + h];
        ev = ev > 0.f ? ev : 0.2f * ev;
        wBuf[t * 4 + h] = __expf(ev);
      }
    }
    __syncthreads();
    float acc = 0.f;
    for (int j = half; j < cnt; j += 2)
      acc = fmaf(h1[(size_t)msBuf[j] * F1 + col], wBuf[j * 4 + (col >> 5)], acc);
    sacc[half][col] = acc;
    if (t < 4) { float sh = 0.f; for (int j = 0; j < cnt; ++j) sh += wBuf[j * 4 + t]; s1L[t] = sh; }
    __syncthreads();
    if (half == 0) {
      float hv = (sacc[0][col] + sacc[1][col]) / (s1L[col >> 5] + 1e-16f) + b1[col];
      hs[col] = hv > 0.f ? hv : (__expf(hv) - 1.f);   // ELU
    }
    __syncthreads();
    {
      int o = t >> 4, r = t & 15;
      float p = 0.f;
      for (int c = r; c < F1; c += 16) p = fmaf(hs[c], W2[c * FOUT + o], p);
      #pragma unroll
      for (int off = 8; off > 0; off >>= 1) p += __shfl_down(p, off, 16);
      if (r == 0) { h2[(size_t)ci * FOUT + o] = p; h2row[o] = p; }
    }
    __syncthreads();
    if (t < 2) {
      const float* av = t ? att_d2 : att_s2;
      float s = 0.f;
      #pragma unroll
      for (int o = 0; o < FOUT; ++o) s += h2row[o] * av[o];
      if (t == 0) a2s[ci] = s; else a2d[ci] = s;
    }
    __syncthreads();
  }
}

// layer-2 attention + aggregation + root gather, all-in-one (single block, LDS acc)
__global__ __launch_bounds__(256) void gat_e2out(
    const float* __restrict__ b2, int* ws, float* __restrict__ out) {
  __shared__ float acc2[GG * FOUT];
  __shared__ float sL[GG];
  __shared__ float a2dR[GG];
  __shared__ float wE[2048];
  int t = threadIdx.x;
  float* a2s = (float*)(ws + O_A2S);
  float* a2d = (float*)(ws + O_A2D);
  float* h2  = (float*)(ws + O_H2);
  int l2 = ws[O_CNT + 3]; if (l2 > L2CAP) l2 = L2CAP;
  for (int i = t; i < GG * FOUT; i += 256) acc2[i] = 0.f;
  for (int i = t; i < GG; i += 256) {
    sL[i] = 0.f;
    unsigned int r = (unsigned int)ws[O_ROOT + i];
    int m = (r < NN) ? ws[O_MAP1 + (int)r] : 0;
    if ((unsigned)m >= C1CAP) m = 0;
    a2dR[i] = a2d[m];
  }
  __syncthreads();
  for (int cb = 0; cb < l2; cb += 2048) {
    int cc = min(2048, l2 - cb);
    for (int i = t; i < cc; i += 256) {
      int s = ws[O_L2 + 2*(cb + i)], g = ws[O_L2 + 2*(cb + i) + 1];
      int msi = ws[O_MAP1 + s]; if ((unsigned)msi >= C1CAP) msi = 0;
      float e = a2s[msi] + a2dR[g];
      e = e > 0.f ? e : 0.2f * e;
      float w = __expf(e);
      wE[i] = w;
      atomicAdd(&sL[g], w);
    }
    __syncthreads();
    for (int idx = t; idx < cc * FOUT; idx += 256) {
      int i = idx >> 4, o = idx & 15;
      int s = ws[O_L2 + 2*(cb + i)], g = ws[O_L2 + 2*(cb + i) + 1];
      int msi = ws[O_MAP1 + s]; if ((unsigned)msi >= C1CAP) msi = 0;
      atomicAdd(&acc2[g * FOUT + o], h2[(size_t)msi * FOUT + o] * wE[i]);
    }
    __syncthreads();
  }
  for (int i = t; i < GG * FOUT; i += 256) {
    int g = i >> 4, o = i & 15;
    out[i] = acc2[i] / (sL[g] + 1e-16f) + b2[o];
  }
}

extern "C" void kernel_launch(void* const* d_in, const int* in_sizes, int n_in,
                              void* d_out, int out_size, void* d_ws, size_t ws_size,
                              hipStream_t stream) {
  const float* x    = (const float*)d_in[0];
  const int*   ei   = (const int*)d_in[1];
  const int*   batch= (const int*)d_in[2];
  const float* W1   = (const float*)d_in[3];
  const float* as1  = (const float*)d_in[4];
  const float* ad1  = (const float*)d_in[5];
  const float* b1   = (const float*)d_in[6];
  const float* W2   = (const float*)d_in[7];
  const float* as2  = (const float*)d_in[8];
  const float* ad2  = (const float*)d_in[9];
  const float* b2   = (const float*)d_in[10];
  float* out = (float*)d_out;
  int* ws = (int*)d_ws;

  hipMemsetAsync(ws, 0, (size_t)O_ZEND * 4, stream);
  hipMemsetAsync(ws + O_ROOT, 0xFF, (size_t)GG * 4, stream);
  gat_roots<<<(NN + 255) / 256, 256, 0, stream>>>(x, batch, ws);
  gat_scan2<<<1024, 256, 0, stream>>>(ei, ws);
  gat_scan1<<<1024, 256, 0, stream>>>(ei, ws);
  gat_h1lin<<<C0CAP / NT, 256, 0, stream>>>(x, W1, as1, ad1, ws);
  gat_e1agg<<<2048, 256, 0, stream>>>(b1, W2, as2, ad2, ws);
  gat_e2out<<<1, 256, 0, stream>>>(b2, ws, out);
}

// Round 12
// 274.172 us; speedup vs baseline: 1.1196x; 1.1196x over previous
//
#include <hip/hip_runtime.h>
#include <math.h>

#define NN 100000
#define EE 1600000
#define GG 100
#define DIN 128
#define F1 128
#define FOUT 16

#define C1CAP 16384
#define C0CAP 49152
#define L2CAP 32768
#define DEGCAP 128   // max in-degree per S1 dst (mean ~17, Poisson; 128 is >±25 sigma)
#define NT 16        // nodes per h1lin tile

// ---- workspace layout (word offsets) ----
// zeroed region (single memset):
#define O_CNT      0                         // [0]=c1,[1]=c0,[3]=l2,[6]=done2,[7]=done
#define O_FLAG1    (O_CNT + 8)               // int[NN]
#define O_FLAG0    (O_FLAG1 + NN)            // int[NN]
#define O_ISROOT   (O_FLAG0 + NN)            // int[NN]  (g+1, 0 = not root)
#define O_FILL     (O_ISROOT + NN)           // int[C1CAP]
#define O_ACC2     (O_FILL + C1CAP)          // float[GG*FOUT] global merge acc
#define O_SL       (O_ACC2 + GG*FOUT)        // float[GG]
#define O_ZEND     (O_SL + GG)
// 0xFF region:
#define O_ROOT     (O_ZEND)                  // uint[GG]
// written-before-read:
#define O_MAP1     (O_ROOT + GG)             // int[NN]
#define O_MAP0     (O_MAP1 + NN)             // int[NN]
#define O_LIST1    (O_MAP0 + NN)             // int[C1CAP]
#define O_LIST0    (O_LIST1 + C1CAP)         // int[C0CAP]
#define O_L2       (O_LIST0 + C0CAP)         // int[L2CAP*2] (src, g)
#define O_ORDER    (O_L2 + L2CAP*2)          // int[C1CAP*DEGCAP] src nodes per dst
#define O_H1       (O_ORDER + C1CAP*DEGCAP)  // float[C0CAP*F1]
#define O_A1S      (O_H1 + C0CAP*F1)         // float[C0CAP*4]
#define O_A1D      (O_A1S + C0CAP*4)         // float[C0CAP*4]
#define O_H2       (O_A1D + C0CAP*4)         // float[C1CAP*FOUT]
#define O_A2S      (O_H2 + C1CAP*FOUT)       // float[C1CAP]
#define O_A2D      (O_A2S + C1CAP)           // float[C1CAP]
#define O_END      (O_A2D + C1CAP)

// roots: group-min of nodes with x[:,0]==0; last block claims roots (fused mark)
__global__ __launch_bounds__(256) void gat_roots(
    const float* __restrict__ x, const int* __restrict__ batch, int* ws) {
  int i = blockIdx.x * blockDim.x + threadIdx.x;
  if (i < NN && x[(size_t)i * DIN] == 0.f)
    atomicMin((unsigned int*)&ws[O_ROOT + batch[i]], (unsigned int)i);
  __threadfence();
  __syncthreads();
  __shared__ int lastFlag;
  if (threadIdx.x == 0)
    lastFlag = (atomicAdd(&ws[O_CNT + 7], 1) == (int)gridDim.x - 1);
  __syncthreads();
  if (!lastFlag) return;
  int g = threadIdx.x;
  if (g >= GG) return;
  unsigned int r = __hip_atomic_load((unsigned int*)&ws[O_ROOT + g],
                                     __ATOMIC_ACQUIRE, __HIP_MEMORY_SCOPE_AGENT);
  if (r >= NN) return;
  ws[O_ISROOT + r] = g + 1;
  ws[O_FLAG1 + r] = 1;
  int idx = atomicAdd(&ws[O_CNT + 0], 1);
  if (idx < C1CAP) {
    ws[O_MAP1 + r] = idx;
    ws[O_LIST1 + idx] = r;
    ws[O_FILL + idx] = 1;                 // layer-1 self-loop pre-seeded
    ws[O_ORDER + idx * DEGCAP] = (int)r;
  }
  int p = atomicAdd(&ws[O_CNT + 3], 1);   // layer-2 self-loop (r -> g)
  if (p < L2CAP) { ws[O_L2 + 2*p] = (int)r; ws[O_L2 + 2*p + 1] = g; }
  ws[O_FLAG0 + r] = 1;
  int i0 = atomicAdd(&ws[O_CNT + 1], 1);
  if (i0 < C0CAP) { ws[O_MAP0 + r] = i0; ws[O_LIST0 + i0] = (int)r; }
}

// scan2: edges into roots -> L2 pairs (src,g); claim srcs into S1 (+S0, +self-loop)
#define SB2 1600
__global__ __launch_bounds__(256) void gat_scan2(const int* __restrict__ ei, int* __restrict__ ws) {
  __shared__ int sp[SB2 * 2];
  __shared__ int sc[SB2];
  __shared__ int nP, nC, bP, bC, b0;
  if (threadIdx.x == 0) { nP = 0; nC = 0; }
  __syncthreads();
  const int perBlock = (EE + gridDim.x - 1) / gridDim.x;   // 1563 <= SB2
  const int beg = blockIdx.x * perBlock;
  const int end = min(beg + perBlock, EE);
  for (int e = beg + threadIdx.x; e < end; e += 256) {
    int d = ei[EE + e];
    int gi = ws[O_ISROOT + d];
    if (gi) {
      int s = ei[e];
      int p = atomicAdd(&nP, 1);
      sp[2*p] = s; sp[2*p + 1] = gi - 1;
      if (atomicCAS(&ws[O_FLAG1 + s], 0, 1) == 0)
        sc[atomicAdd(&nC, 1)] = s;
    }
  }
  __syncthreads();
  if (threadIdx.x == 0) {
    bP = nP ? atomicAdd(&ws[O_CNT + 3], nP) : 0;
    bC = nC ? atomicAdd(&ws[O_CNT + 0], nC) : 0;
    b0 = nC ? atomicAdd(&ws[O_CNT + 1], nC) : 0;
  }
  __syncthreads();
  for (int i = threadIdx.x; i < nP; i += 256) {
    int p = bP + i;
    if (p < L2CAP) { ws[O_L2 + 2*p] = sp[2*i]; ws[O_L2 + 2*p + 1] = sp[2*i + 1]; }
  }
  for (int i = threadIdx.x; i < nC; i += 256) {
    int node = sc[i], idx = bC + i, i0 = b0 + i;
    if (idx < C1CAP) {
      ws[O_MAP1 + node] = idx;
      ws[O_LIST1 + idx] = node;
      ws[O_FILL + idx] = 1;               // self-loop
      ws[O_ORDER + idx * DEGCAP] = node;
    }
    ws[O_FLAG0 + node] = 1;               // unique nodes: plain store ok
    if (i0 < C0CAP) { ws[O_MAP0 + node] = i0; ws[O_LIST0 + i0] = node; }
  }
}

// scan1: edges into S1 -> direct scatter into per-dst slots; claim srcs into S0
__global__ __launch_bounds__(256) void gat_scan1(const int* __restrict__ ei, int* __restrict__ ws) {
  __shared__ int sc[SB2];
  __shared__ int nC, b0;
  if (threadIdx.x == 0) nC = 0;
  __syncthreads();
  const int perBlock = (EE + gridDim.x - 1) / gridDim.x;
  const int beg = blockIdx.x * perBlock;
  const int end = min(beg + perBlock, EE);
  for (int e = beg + threadIdx.x; e < end; e += 256) {
    int d = ei[EE + e];
    if (ws[O_FLAG1 + d]) {
      int s = ei[e];
      int md1 = ws[O_MAP1 + d];
      if ((unsigned)md1 < C1CAP) {
        int pos = atomicAdd(&ws[O_FILL + md1], 1);
        if (pos < DEGCAP) ws[O_ORDER + md1 * DEGCAP + pos] = s;
      }
      if (atomicCAS(&ws[O_FLAG0 + s], 0, 1) == 0)
        sc[atomicAdd(&nC, 1)] = s;
    }
  }
  __syncthreads();
  if (threadIdx.x == 0) b0 = nC ? atomicAdd(&ws[O_CNT + 1], nC) : 0;
  __syncthreads();
  for (int i = threadIdx.x; i < nC; i += 256) {
    int node = sc[i], i0 = b0 + i;
    if (i0 < C0CAP) { ws[O_MAP0 + node] = i0; ws[O_LIST0 + i0] = node; }
  }
}

// h1lin: 16-node tiles, x in LDS, W1 streamed (L1/L2); 8 nodes x 1 col per thread
__global__ __launch_bounds__(256) void gat_h1lin(
    const float* __restrict__ x, const float* __restrict__ W1,
    const float* __restrict__ att_s1, const float* __restrict__ att_d1, int* ws) {
  __shared__ float xs[NT][DIN];   // 8 KB
  int t = threadIdx.x, col = t & 127, half = t >> 7;
  int c0 = ws[O_CNT + 1]; if (c0 > C0CAP) c0 = C0CAP;
  float* h1  = (float*)(ws + O_H1);
  float* a1s = (float*)(ws + O_A1S);
  float* a1d = (float*)(ws + O_A1D);
  float as1v = att_s1[col], ad1v = att_d1[col];
  for (int tile = blockIdx.x * NT; tile < c0; tile += gridDim.x * NT) {
    {
      int n = t >> 4, k0 = (t & 15) * 8;
      int ci = tile + n;
      if (ci < c0) {
        int v = ws[O_LIST0 + ci];
        const float4* src = (const float4*)&x[(size_t)v * DIN + k0];
        *(float4*)&xs[n][k0]     = src[0];
        *(float4*)&xs[n][k0 + 4] = src[1];
      }
    }
    __syncthreads();
    float acc[8];
    #pragma unroll
    for (int i = 0; i < 8; ++i) acc[i] = 0.f;
    #pragma unroll 4
    for (int k = 0; k < DIN; k += 4) {
      float w0 = W1[(k + 0) * F1 + col];
      float w1 = W1[(k + 1) * F1 + col];
      float w2 = W1[(k + 2) * F1 + col];
      float w3 = W1[(k + 3) * F1 + col];
      #pragma unroll
      for (int n8 = 0; n8 < 8; ++n8) {
        const float4 xv = *(const float4*)&xs[half * 8 + n8][k];
        acc[n8] = fmaf(xv.x, w0, acc[n8]);
        acc[n8] = fmaf(xv.y, w1, acc[n8]);
        acc[n8] = fmaf(xv.z, w2, acc[n8]);
        acc[n8] = fmaf(xv.w, w3, acc[n8]);
      }
    }
    #pragma unroll
    for (int n8 = 0; n8 < 8; ++n8) {
      int ci = tile + half * 8 + n8;
      bool ok = ci < c0;
      if (ok) h1[(size_t)ci * F1 + col] = acc[n8];
      float cs = acc[n8] * as1v, cd = acc[n8] * ad1v;
      #pragma unroll
      for (int off = 16; off > 0; off >>= 1) {
        cs += __shfl_down(cs, off, 32);
        cd += __shfl_down(cd, off, 32);
      }
      if (ok && (col & 31) == 0) {
        a1s[ci * 4 + (col >> 5)] = cs;
        a1d[ci * 4 + (col >> 5)] = cd;
      }
    }
    __syncthreads();
  }
}

// e1agg (+fused layer-1 finalize + layer-2 linear): one block per S1 dst
__global__ __launch_bounds__(256) void gat_e1agg(
    const float* __restrict__ b1, const float* __restrict__ W2,
    const float* __restrict__ att_s2, const float* __restrict__ att_d2, int* ws) {
  int c1 = ws[O_CNT + 0]; if (c1 > C1CAP) c1 = C1CAP;
  float* a1s = (float*)(ws + O_A1S);
  float* a1d = (float*)(ws + O_A1D);
  float* h1  = (float*)(ws + O_H1);
  float* h2  = (float*)(ws + O_H2);
  float* a2s = (float*)(ws + O_A2S);
  float* a2d = (float*)(ws + O_A2D);
  __shared__ int   msBuf[DEGCAP];
  __shared__ float wBuf[DEGCAP * 4];
  __shared__ float sacc[2][F1];
  __shared__ float hs[F1];
  __shared__ float s1L[4];
  __shared__ float h2row[FOUT];
  int t = threadIdx.x, col = t & 127, half = t >> 7;
  for (int ci = blockIdx.x; ci < c1; ci += gridDim.x) {
    int cnt = ws[O_FILL + ci]; if (cnt > DEGCAP) cnt = DEGCAP;
    int node = ws[O_LIST1 + ci];
    int md0 = ws[O_MAP0 + node]; if ((unsigned)md0 >= C0CAP) md0 = 0;
    if (t < cnt) {
      int srcn = ws[O_ORDER + ci * DEGCAP + t];
      int ms = ws[O_MAP0 + srcn]; if ((unsigned)ms >= C0CAP) ms = 0;
      msBuf[t] = ms;
      #pragma unroll
      for (int h = 0; h < 4; ++h) {
        float ev = a1s[ms * 4 + h] + a1d[md0 * 4 + h];
        ev = ev > 0.f ? ev : 0.2f * ev;
        wBuf[t * 4 + h] = __expf(ev);
      }
    }
    __syncthreads();
    float acc = 0.f;
    for (int j = half; j < cnt; j += 2)
      acc = fmaf(h1[(size_t)msBuf[j] * F1 + col], wBuf[j * 4 + (col >> 5)], acc);
    sacc[half][col] = acc;
    if (t < 4) { float sh = 0.f; for (int j = 0; j < cnt; ++j) sh += wBuf[j * 4 + t]; s1L[t] = sh; }
    __syncthreads();
    if (half == 0) {
      float hv = (sacc[0][col] + sacc[1][col]) / (s1L[col >> 5] + 1e-16f) + b1[col];
      hs[col] = hv > 0.f ? hv : (__expf(hv) - 1.f);   // ELU
    }
    __syncthreads();
    {
      int o = t >> 4, r = t & 15;
      float p = 0.f;
      for (int c = r; c < F1; c += 16) p = fmaf(hs[c], W2[c * FOUT + o], p);
      #pragma unroll
      for (int off = 8; off > 0; off >>= 1) p += __shfl_down(p, off, 16);
      if (r == 0) { h2[(size_t)ci * FOUT + o] = p; h2row[o] = p; }
    }
    __syncthreads();
    if (t < 2) {
      const float* av = t ? att_d2 : att_s2;
      float s = 0.f;
      #pragma unroll
      for (int o = 0; o < FOUT; ++o) s += h2row[o] * av[o];
      if (t == 0) a2s[ci] = s; else a2d[ci] = s;
    }
    __syncthreads();
  }
}

// layer-2 attention + aggregation + root gather: grid-parallel, last block finalizes
#define E2CH 64   // pairs per block-chunk
__global__ __launch_bounds__(256) void gat_e2out(
    const float* __restrict__ b2, int* ws, float* __restrict__ out) {
  __shared__ float acc2[GG * FOUT];   // 6.4 KB
  __shared__ float sL[GG];
  __shared__ float a2dR[GG];
  __shared__ int lastFlag;
  int t = threadIdx.x;
  float* a2s  = (float*)(ws + O_A2S);
  float* a2d  = (float*)(ws + O_A2D);
  float* h2   = (float*)(ws + O_H2);
  float* gacc = (float*)(ws + O_ACC2);
  float* gsl  = (float*)(ws + O_SL);
  int l2 = ws[O_CNT + 3]; if (l2 > L2CAP) l2 = L2CAP;
  for (int i = t; i < GG * FOUT; i += 256) acc2[i] = 0.f;
  for (int i = t; i < GG; i += 256) {
    sL[i] = 0.f;
    unsigned int r = (unsigned int)ws[O_ROOT + i];
    int m = (r < NN) ? ws[O_MAP1 + (int)r] : 0;
    if ((unsigned)m >= C1CAP) m = 0;
    a2dR[i] = a2d[m];
  }
  __syncthreads();
  // pair processing: 4 threads per pair (sub = t>>6 covers 4 output chans each)
  bool touched = false;
  int pi = t & 63, sub = t >> 6;
  for (int base = blockIdx.x * E2CH; base < l2; base += gridDim.x * E2CH) {
    int i = base + pi;
    if (pi < E2CH && i < l2) {
      int s = ws[O_L2 + 2*i], g = ws[O_L2 + 2*i + 1];
      int msi = ws[O_MAP1 + s]; if ((unsigned)msi >= C1CAP) msi = 0;
      float e = a2s[msi] + a2dR[g];
      e = e > 0.f ? e : 0.2f * e;
      float w = __expf(e);
      if (sub == 0) atomicAdd(&sL[g], w);
      #pragma unroll
      for (int oo = 0; oo < 4; ++oo) {
        int o = sub * 4 + oo;
        atomicAdd(&acc2[g * FOUT + o], h2[(size_t)msi * FOUT + o] * w);
      }
      touched = true;
    }
  }
  __syncthreads();
  // merge into global accumulators (skip if this block saw no pairs)
  if (__syncthreads_or(touched)) {
    for (int i = t; i < GG * FOUT; i += 256) atomicAdd(&gacc[i], acc2[i]);
    for (int i = t; i < GG; i += 256) atomicAdd(&gsl[i], sL[i]);
  }
  __threadfence();
  __syncthreads();
  if (t == 0)
    lastFlag = (atomicAdd(&ws[O_CNT + 6], 1) == (int)gridDim.x - 1);
  __syncthreads();
  if (!lastFlag) return;
  for (int i = t; i < GG * FOUT; i += 256) {
    int g = i >> 4, o = i & 15;
    float a = __hip_atomic_load(&gacc[i], __ATOMIC_ACQUIRE, __HIP_MEMORY_SCOPE_AGENT);
    float sden = __hip_atomic_load(&gsl[g], __ATOMIC_ACQUIRE, __HIP_MEMORY_SCOPE_AGENT);
    out[i] = a / (sden + 1e-16f) + b2[o];
  }
}

extern "C" void kernel_launch(void* const* d_in, const int* in_sizes, int n_in,
                              void* d_out, int out_size, void* d_ws, size_t ws_size,
                              hipStream_t stream) {
  const float* x    = (const float*)d_in[0];
  const int*   ei   = (const int*)d_in[1];
  const int*   batch= (const int*)d_in[2];
  const float* W1   = (const float*)d_in[3];
  const float* as1  = (const float*)d_in[4];
  const float* ad1  = (const float*)d_in[5];
  const float* b1   = (const float*)d_in[6];
  const float* W2   = (const float*)d_in[7];
  const float* as2  = (const float*)d_in[8];
  const float* ad2  = (const float*)d_in[9];
  const float* b2   = (const float*)d_in[10];
  float* out = (float*)d_out;
  int* ws = (int*)d_ws;

  hipMemsetAsync(ws, 0, (size_t)O_ZEND * 4, stream);
  hipMemsetAsync(ws + O_ROOT, 0xFF, (size_t)GG * 4, stream);
  gat_roots<<<(NN + 255) / 256, 256, 0, stream>>>(x, batch, ws);
  gat_scan2<<<1024, 256, 0, stream>>>(ei, ws);
  gat_scan1<<<1024, 256, 0, stream>>>(ei, ws);
  gat_h1lin<<<C0CAP / NT, 256, 0, stream>>>(x, W1, as1, ad1, ws);
  gat_e1agg<<<2048, 256, 0, stream>>>(b1, W2, as2, ad2, ws);
  gat_e2out<<<256, 256, 0, stream>>>(b2, ws, out);
}